// Round 4
// baseline (144.693 us; speedup 1.0000x reference)
//
#include <hip/hip_runtime.h>
#include <math.h>

// MaskedConvFlow — bf16 MFMA, 4-row strip blocks.
// x:  [32][64][64][64] f32. Wm -> WmR bf16 [kh][kw][co][ci]. W1 -> W1b bf16 [o][k].
// Block = (b, strip of 4 h-rows). 512 blocks (2/CU), 512 threads (8 waves).
// Stage Xt[slot=0..4][wp=0..65][ci] bf16 (input rows h0-2..h0+2, chunk-XOR
// swizzled). Per row: GEMM1 = 6 shifted (kh,kw) GEMMs K=64 -> Ct[w][co] bf16;
// GEMM2 (K=256) + fused sigmoid/affine/logdet epilogue in registers.

#define BATCH 32
#define HDIM 64
#define WDIM 64
#define ROWS 4
#define STRIPS 16
#define NBLK (BATCH * STRIPS)   // 512
#define CT_LD 264               // 256 + 8 pad shorts

typedef __attribute__((ext_vector_type(8))) short short8;
typedef __attribute__((ext_vector_type(4))) float f32x4;

__device__ inline unsigned short f2bf(float f) {
    union { float f; unsigned int u; } v; v.f = f;
    unsigned int u = v.u;
    unsigned int r = u + 0x7FFFu + ((u >> 16) & 1u);   // RNE
    return (unsigned short)(r >> 16);
}

// Xt element offset (in shorts): chunk-XOR swizzle for conflict-free b128 reads
__device__ inline int xt_off(int slot, int wp, int ci) {
    return ((slot * 66 + wp) << 6) + ((((ci >> 3) ^ (wp & 7)) << 3) | (ci & 7));
}

// ---- prep: weight convert/repack ----
// WmR[((kh*3+kw)*256+co)*64+ci] = bf16(Wm[co][ci][kh][kw]); W1b[o][k] = bf16(W1)
__global__ __launch_bounds__(256) void mcf_prep(
    const float* __restrict__ Wm, const float* __restrict__ W1,
    unsigned short* __restrict__ WmR, unsigned short* __restrict__ W1b)
{
    int idx = blockIdx.x * 256 + threadIdx.x;     // grid covers 131072
    if (idx < 6 * 256 * 64) {
        int khkw = idx >> 14;
        int rem = idx & 16383;
        int co = rem >> 6;
        int ci = rem & 63;
        int kh = khkw / 3, kw = khkw % 3;
        WmR[idx] = f2bf(Wm[((co * 64 + ci) * 2 + kh) * 3 + kw]);
    } else {
        int i = idx - 6 * 256 * 64;
        W1b[i] = f2bf(W1[i]);
    }
}

__global__ __launch_bounds__(512, 4) void mcf_mfma(
    const float* __restrict__ x,
    const unsigned short* __restrict__ WmR,
    const float* __restrict__ bm,
    const unsigned short* __restrict__ W1b,
    const float* __restrict__ b1,
    float* __restrict__ out, float* __restrict__ row_ld)
{
    __shared__ __align__(16) unsigned short Xt[5 * 66 * 64];   // 42240 B
    __shared__ __align__(16) unsigned short Ct[64 * CT_LD];    // 33792 B
    __shared__ float red[8];

    const int blk = blockIdx.x;
    const int b = blk >> 4;
    const int h0 = (blk & 15) * ROWS;
    const int tid = threadIdx.x;
    const int lane = tid & 63;
    const int wv = tid >> 6;
    const int col = lane & 15;
    const int g = lane >> 4;

    // ---- zero pad wp = 0 and wp = 65 for ALL 5 slots (640 entries, 512 thr) ----
    for (int l = tid; l < 640; l += 512) {
        int s = l >> 7, rr = l & 127;
        int wp = (rr >= 64) ? 65 : 0, ci = rr & 63;
        Xt[xt_off(s, wp, ci)] = 0;
    }
    // ---- stage 5 input rows (h0-2 .. h0+2), coalesced, one batch ----
    #pragma unroll
    for (int it = 0; it < 40; ++it) {
        int idx = it * 512 + tid;          // 20480 = 5 slots * 64 ci * 64 w
        int w = idx & 63;
        int ci = (idx >> 6) & 63;
        int slot = idx >> 12;
        int row = h0 - 2 + slot;
        float v = 0.f;
        if (row >= 0) v = x[(((size_t)b * 64 + ci) * 64 + row) * 64 + w];
        Xt[xt_off(slot, w + 1, ci)] = f2bf(v);
    }
    __syncthreads();

    // ---- hoisted biases ----
    float bs1[2][4];
    #pragma unroll
    for (int ct = 0; ct < 2; ++ct)
        #pragma unroll
        for (int j = 0; j < 4; ++j) bs1[ct][j] = bm[wv * 32 + ct * 16 + g * 4 + j];
    const int pr = wv & 3;       // GEMM2 mu row-tile; ls = pr+4
    const int wcg = wv >> 2;     // GEMM2 w-tile group
    float bMu[4], bLs[4];
    #pragma unroll
    for (int j = 0; j < 4; ++j) {
        bMu[j] = b1[pr * 16 + g * 4 + j];
        bLs[j] = b1[64 + pr * 16 + g * 4 + j];
    }

    float ldacc = 0.f;

    #pragma unroll 1
    for (int r = 0; r < ROWS; ++r) {
        // ---- GEMM1: 6 shifted (kh,kw) GEMMs, K=64 each ----
        f32x4 acc[2][4];
        #pragma unroll
        for (int ct = 0; ct < 2; ++ct)
            #pragma unroll
            for (int wt = 0; wt < 4; ++wt)
                #pragma unroll
                for (int j = 0; j < 4; ++j) acc[ct][wt][j] = bs1[ct][j];

        #pragma unroll
        for (int kh = 0; kh < 2; ++kh) {
            #pragma unroll
            for (int kw = 0; kw < 3; ++kw) {
                const unsigned short* wmk = WmR + ((kh * 3 + kw) << 14);
                #pragma unroll
                for (int ks = 0; ks < 2; ++ks) {
                    short8 bfrag[4];
                    #pragma unroll
                    for (int wt = 0; wt < 4; ++wt) {
                        int wp = wt * 16 + col + kw;
                        bfrag[wt] = *reinterpret_cast<const short8*>(
                            &Xt[(((r + kh) * 66 + wp) << 6) + ((((ks * 4 + g) ^ (wp & 7)) << 3))]);
                    }
                    #pragma unroll
                    for (int ct = 0; ct < 2; ++ct) {
                        short8 af = *reinterpret_cast<const short8*>(
                            &wmk[(wv * 32 + ct * 16 + col) * 64 + ks * 32 + g * 8]);
                        #pragma unroll
                        for (int wt = 0; wt < 4; ++wt)
                            acc[ct][wt] = __builtin_amdgcn_mfma_f32_16x16x32_bf16(
                                af, bfrag[wt], acc[ct][wt], 0, 0, 0);
                    }
                }
            }
        }
        // relu -> bf16 -> Ct[w][co]
        #pragma unroll
        for (int ct = 0; ct < 2; ++ct) {
            int co_base = wv * 32 + ct * 16 + g * 4;
            #pragma unroll
            for (int wt = 0; wt < 4; ++wt) {
                int w = wt * 16 + col;
                unsigned short pk[4];
                #pragma unroll
                for (int j = 0; j < 4; ++j) pk[j] = f2bf(fmaxf(acc[ct][wt][j], 0.f));
                *reinterpret_cast<unsigned long long*>(&Ct[w * CT_LD + co_base]) =
                    *reinterpret_cast<const unsigned long long*>(pk);
            }
        }
        __syncthreads();

        // ---- GEMM2 + fused epilogue (row h0+r) ----
        f32x4 accM[2], accL[2];
        #pragma unroll
        for (int j = 0; j < 4; ++j) {
            accM[0][j] = bMu[j]; accM[1][j] = bMu[j];
            accL[0][j] = bLs[j]; accL[1][j] = bLs[j];
        }
        #pragma unroll
        for (int ks = 0; ks < 8; ++ks) {
            int kk = ks * 32 + g * 8;
            short8 bf2[2];
            #pragma unroll
            for (int wt = 0; wt < 2; ++wt) {
                int w = (wcg * 2 + wt) * 16 + col;
                bf2[wt] = *reinterpret_cast<const short8*>(&Ct[w * CT_LD + kk]);
            }
            int oA = pr * 16 + col;
            short8 aM = *reinterpret_cast<const short8*>(&W1b[oA * 256 + kk]);
            short8 aL = *reinterpret_cast<const short8*>(&W1b[(oA + 64) * 256 + kk]);
            #pragma unroll
            for (int wt = 0; wt < 2; ++wt) {
                accM[wt] = __builtin_amdgcn_mfma_f32_16x16x32_bf16(aM, bf2[wt], accM[wt], 0, 0, 0);
                accL[wt] = __builtin_amdgcn_mfma_f32_16x16x32_bf16(aL, bf2[wt], accL[wt], 0, 0, 0);
            }
        }
        int h = h0 + r;
        #pragma unroll
        for (int wt = 0; wt < 2; ++wt) {
            int w = (wcg * 2 + wt) * 16 + col;
            #pragma unroll
            for (int j = 0; j < 4; ++j) {
                int co = pr * 16 + g * 4 + j;
                float mu = accM[wt][j];
                float ls = accL[wt][j];
                float scale = 1.f / (1.f + __expf(-(ls + 2.f)));
                size_t xi = (((size_t)b * 64 + co) * 64 + h) * 64 + w;
                out[xi] = scale * x[xi] + mu;
                ldacc += __logf(scale);
            }
        }
        __syncthreads();   // Ct free for next row
    }

    // ---- logdet partial for this strip ----
    #pragma unroll
    for (int off = 32; off; off >>= 1) ldacc += __shfl_down(ldacc, off);
    if (lane == 0) red[wv] = ldacc;
    __syncthreads();
    if (tid == 0) {
        float s = 0.f;
        #pragma unroll
        for (int i = 0; i < 8; ++i) s += red[i];
        row_ld[blk] = s;
    }
}

__global__ __launch_bounds__(64) void mcf_ldreduce(
    const float* __restrict__ row_ld, float* __restrict__ ldout)
{
    int b = blockIdx.x;
    int l = threadIdx.x;
    float v = (l < STRIPS) ? row_ld[b * STRIPS + l] : 0.f;
    #pragma unroll
    for (int off = 32; off; off >>= 1) v += __shfl_down(v, off);
    if (l == 0) ldout[b] = v;
}

extern "C" void kernel_launch(void* const* d_in, const int* in_sizes, int n_in,
                              void* d_out, int out_size, void* d_ws, size_t ws_size,
                              hipStream_t stream) {
    const float* x  = (const float*)d_in[0];
    const float* Wm = (const float*)d_in[1];
    const float* bm = (const float*)d_in[2];
    const float* W1 = (const float*)d_in[3];
    const float* b1 = (const float*)d_in[4];
    float* out = (float*)d_out;

    float* row_ld = (float*)d_ws;                                   // 2048 B
    unsigned short* WmR = (unsigned short*)((char*)d_ws + 8192);    // 196608 B
    unsigned short* W1b = WmR + 6 * 256 * 64;                       // 65536 B

    hipLaunchKernelGGL(mcf_prep, dim3(512), dim3(256), 0, stream,
                       Wm, W1, WmR, W1b);
    hipLaunchKernelGGL(mcf_mfma, dim3(NBLK), dim3(512), 0, stream,
                       x, WmR, bm, W1b, b1, out, row_ld);
    hipLaunchKernelGGL(mcf_ldreduce, dim3(BATCH), dim3(64), 0, stream,
                       row_ld, out + (size_t)BATCH * 64 * HDIM * WDIM);
}

// Round 5
// 74.716 us; speedup vs baseline: 1.9366x; 1.9366x over previous
//
#include <hip/hip_runtime.h>
#include <math.h>

// MaskedConvFlow — bf16 MFMA, 4-row strip blocks.
// x:  [32][64][64][64] f32. Wm -> WmR bf16 [kh][kw][co][ci]. W1 -> W1b bf16 [o][k].
// Block = (b, strip of 4 h-rows). 512 blocks (2/CU), 512 threads (8 waves).
// Stage Xt[slot=0..4][wp=0..65][ci] bf16 (input rows h0-2..h0+2, chunk-XOR
// swizzled). Per row: GEMM1 = 6 shifted (kh,kw) GEMMs K=64 -> Ct[w][co] bf16;
// GEMM2 (K=256) + fused sigmoid/affine/logdet epilogue in registers.
// R5 change vs R4: __launch_bounds__(512,2) — drop the 128-reg unified-file cap
// that (theory) forced scratch spills (FETCH 304MB/WRITE 181MB symmetric excess).

#define BATCH 32
#define HDIM 64
#define WDIM 64
#define ROWS 4
#define STRIPS 16
#define NBLK (BATCH * STRIPS)   // 512
#define CT_LD 264               // 256 + 8 pad shorts

typedef __attribute__((ext_vector_type(8))) short short8;
typedef __attribute__((ext_vector_type(4))) float f32x4;

__device__ inline unsigned short f2bf(float f) {
    union { float f; unsigned int u; } v; v.f = f;
    unsigned int u = v.u;
    unsigned int r = u + 0x7FFFu + ((u >> 16) & 1u);   // RNE
    return (unsigned short)(r >> 16);
}

// Xt element offset (in shorts): chunk-XOR swizzle for conflict-free b128 reads
__device__ inline int xt_off(int slot, int wp, int ci) {
    return ((slot * 66 + wp) << 6) + ((((ci >> 3) ^ (wp & 7)) << 3) | (ci & 7));
}

// ---- prep: weight convert/repack ----
// WmR[((kh*3+kw)*256+co)*64+ci] = bf16(Wm[co][ci][kh][kw]); W1b[o][k] = bf16(W1)
__global__ __launch_bounds__(256) void mcf_prep(
    const float* __restrict__ Wm, const float* __restrict__ W1,
    unsigned short* __restrict__ WmR, unsigned short* __restrict__ W1b)
{
    int idx = blockIdx.x * 256 + threadIdx.x;     // grid covers 131072
    if (idx < 6 * 256 * 64) {
        int khkw = idx >> 14;
        int rem = idx & 16383;
        int co = rem >> 6;
        int ci = rem & 63;
        int kh = khkw / 3, kw = khkw % 3;
        WmR[idx] = f2bf(Wm[((co * 64 + ci) * 2 + kh) * 3 + kw]);
    } else {
        int i = idx - 6 * 256 * 64;
        W1b[i] = f2bf(W1[i]);
    }
}

__global__ __launch_bounds__(512, 2) void mcf_mfma(
    const float* __restrict__ x,
    const unsigned short* __restrict__ WmR,
    const float* __restrict__ bm,
    const unsigned short* __restrict__ W1b,
    const float* __restrict__ b1,
    float* __restrict__ out, float* __restrict__ row_ld)
{
    __shared__ __align__(16) unsigned short Xt[5 * 66 * 64];   // 42240 B
    __shared__ __align__(16) unsigned short Ct[64 * CT_LD];    // 33792 B
    __shared__ float red[8];

    const int blk = blockIdx.x;
    const int b = blk >> 4;
    const int h0 = (blk & 15) * ROWS;
    const int tid = threadIdx.x;
    const int lane = tid & 63;
    const int wv = tid >> 6;
    const int col = lane & 15;
    const int g = lane >> 4;

    // ---- zero pad wp = 0 and wp = 65 for ALL 5 slots (640 entries, 512 thr) ----
    for (int l = tid; l < 640; l += 512) {
        int s = l >> 7, rr = l & 127;
        int wp = (rr >= 64) ? 65 : 0, ci = rr & 63;
        Xt[xt_off(s, wp, ci)] = 0;
    }
    // ---- stage 5 input rows (h0-2 .. h0+2), coalesced, one batch ----
    #pragma unroll
    for (int it = 0; it < 40; ++it) {
        int idx = it * 512 + tid;          // 20480 = 5 slots * 64 ci * 64 w
        int w = idx & 63;
        int ci = (idx >> 6) & 63;
        int slot = idx >> 12;
        int row = h0 - 2 + slot;
        float v = 0.f;
        if (row >= 0) v = x[(((size_t)b * 64 + ci) * 64 + row) * 64 + w];
        Xt[xt_off(slot, w + 1, ci)] = f2bf(v);
    }
    __syncthreads();

    // ---- hoisted biases ----
    float bs1[2][4];
    #pragma unroll
    for (int ct = 0; ct < 2; ++ct)
        #pragma unroll
        for (int j = 0; j < 4; ++j) bs1[ct][j] = bm[wv * 32 + ct * 16 + g * 4 + j];
    const int pr = wv & 3;       // GEMM2 mu row-tile; ls = pr+4
    const int wcg = wv >> 2;     // GEMM2 w-tile group
    float bMu[4], bLs[4];
    #pragma unroll
    for (int j = 0; j < 4; ++j) {
        bMu[j] = b1[pr * 16 + g * 4 + j];
        bLs[j] = b1[64 + pr * 16 + g * 4 + j];
    }

    float ldacc = 0.f;

    #pragma unroll 1
    for (int r = 0; r < ROWS; ++r) {
        // ---- GEMM1: 6 shifted (kh,kw) GEMMs, K=64 each ----
        f32x4 acc[2][4];
        #pragma unroll
        for (int ct = 0; ct < 2; ++ct)
            #pragma unroll
            for (int wt = 0; wt < 4; ++wt)
                #pragma unroll
                for (int j = 0; j < 4; ++j) acc[ct][wt][j] = bs1[ct][j];

        #pragma unroll
        for (int kh = 0; kh < 2; ++kh) {
            #pragma unroll
            for (int kw = 0; kw < 3; ++kw) {
                const unsigned short* wmk = WmR + ((kh * 3 + kw) << 14);
                #pragma unroll
                for (int ks = 0; ks < 2; ++ks) {
                    short8 bfrag[4];
                    #pragma unroll
                    for (int wt = 0; wt < 4; ++wt) {
                        int wp = wt * 16 + col + kw;
                        bfrag[wt] = *reinterpret_cast<const short8*>(
                            &Xt[(((r + kh) * 66 + wp) << 6) + ((((ks * 4 + g) ^ (wp & 7)) << 3))]);
                    }
                    #pragma unroll
                    for (int ct = 0; ct < 2; ++ct) {
                        short8 af = *reinterpret_cast<const short8*>(
                            &wmk[(wv * 32 + ct * 16 + col) * 64 + ks * 32 + g * 8]);
                        #pragma unroll
                        for (int wt = 0; wt < 4; ++wt)
                            acc[ct][wt] = __builtin_amdgcn_mfma_f32_16x16x32_bf16(
                                af, bfrag[wt], acc[ct][wt], 0, 0, 0);
                    }
                }
            }
        }
        // relu -> bf16 -> Ct[w][co]
        #pragma unroll
        for (int ct = 0; ct < 2; ++ct) {
            int co_base = wv * 32 + ct * 16 + g * 4;
            #pragma unroll
            for (int wt = 0; wt < 4; ++wt) {
                int w = wt * 16 + col;
                unsigned short pk[4];
                #pragma unroll
                for (int j = 0; j < 4; ++j) pk[j] = f2bf(fmaxf(acc[ct][wt][j], 0.f));
                *reinterpret_cast<unsigned long long*>(&Ct[w * CT_LD + co_base]) =
                    *reinterpret_cast<const unsigned long long*>(pk);
            }
        }
        __syncthreads();

        // ---- GEMM2 + fused epilogue (row h0+r) ----
        f32x4 accM[2], accL[2];
        #pragma unroll
        for (int j = 0; j < 4; ++j) {
            accM[0][j] = bMu[j]; accM[1][j] = bMu[j];
            accL[0][j] = bLs[j]; accL[1][j] = bLs[j];
        }
        #pragma unroll
        for (int ks = 0; ks < 8; ++ks) {
            int kk = ks * 32 + g * 8;
            short8 bf2[2];
            #pragma unroll
            for (int wt = 0; wt < 2; ++wt) {
                int w = (wcg * 2 + wt) * 16 + col;
                bf2[wt] = *reinterpret_cast<const short8*>(&Ct[w * CT_LD + kk]);
            }
            int oA = pr * 16 + col;
            short8 aM = *reinterpret_cast<const short8*>(&W1b[oA * 256 + kk]);
            short8 aL = *reinterpret_cast<const short8*>(&W1b[(oA + 64) * 256 + kk]);
            #pragma unroll
            for (int wt = 0; wt < 2; ++wt) {
                accM[wt] = __builtin_amdgcn_mfma_f32_16x16x32_bf16(aM, bf2[wt], accM[wt], 0, 0, 0);
                accL[wt] = __builtin_amdgcn_mfma_f32_16x16x32_bf16(aL, bf2[wt], accL[wt], 0, 0, 0);
            }
        }
        int h = h0 + r;
        #pragma unroll
        for (int wt = 0; wt < 2; ++wt) {
            int w = (wcg * 2 + wt) * 16 + col;
            #pragma unroll
            for (int j = 0; j < 4; ++j) {
                int co = pr * 16 + g * 4 + j;
                float mu = accM[wt][j];
                float ls = accL[wt][j];
                float scale = 1.f / (1.f + __expf(-(ls + 2.f)));
                size_t xi = (((size_t)b * 64 + co) * 64 + h) * 64 + w;
                out[xi] = scale * x[xi] + mu;
                ldacc += __logf(scale);
            }
        }
        __syncthreads();   // Ct free for next row
    }

    // ---- logdet partial for this strip ----
    #pragma unroll
    for (int off = 32; off; off >>= 1) ldacc += __shfl_down(ldacc, off);
    if (lane == 0) red[wv] = ldacc;
    __syncthreads();
    if (tid == 0) {
        float s = 0.f;
        #pragma unroll
        for (int i = 0; i < 8; ++i) s += red[i];
        row_ld[blk] = s;
    }
}

__global__ __launch_bounds__(64) void mcf_ldreduce(
    const float* __restrict__ row_ld, float* __restrict__ ldout)
{
    int b = blockIdx.x;
    int l = threadIdx.x;
    float v = (l < STRIPS) ? row_ld[b * STRIPS + l] : 0.f;
    #pragma unroll
    for (int off = 32; off; off >>= 1) v += __shfl_down(v, off);
    if (l == 0) ldout[b] = v;
}

extern "C" void kernel_launch(void* const* d_in, const int* in_sizes, int n_in,
                              void* d_out, int out_size, void* d_ws, size_t ws_size,
                              hipStream_t stream) {
    const float* x  = (const float*)d_in[0];
    const float* Wm = (const float*)d_in[1];
    const float* bm = (const float*)d_in[2];
    const float* W1 = (const float*)d_in[3];
    const float* b1 = (const float*)d_in[4];
    float* out = (float*)d_out;

    float* row_ld = (float*)d_ws;                                   // 2048 B
    unsigned short* WmR = (unsigned short*)((char*)d_ws + 8192);    // 196608 B
    unsigned short* W1b = WmR + 6 * 256 * 64;                       // 65536 B

    hipLaunchKernelGGL(mcf_prep, dim3(512), dim3(256), 0, stream,
                       Wm, W1, WmR, W1b);
    hipLaunchKernelGGL(mcf_mfma, dim3(NBLK), dim3(512), 0, stream,
                       x, WmR, bm, W1b, b1, out, row_ld);
    hipLaunchKernelGGL(mcf_ldreduce, dim3(BATCH), dim3(64), 0, stream,
                       row_ld, out + (size_t)BATCH * 64 * HDIM * WDIM);
}